// Round 5
// baseline (1221.012 us; speedup 1.0000x reference)
//
#include <hip/hip_runtime.h>
#include <hip/hip_bf16.h>
#include <cstdint>
#include <cstddef>
#include <type_traits>

// KAN GLU expert: h = kan(x;w1) * kan(x;w2); out = kan(h;w3)
// kan(x;W) == [silu(x_i), B0..B7(x_i)]_i @ [base_w | spline_w]^T
// -> bf16 MFMA GEMMs with K expanded 9x.
//
// GEMM: 256x256 tile, BK=32, ring-4 LDS slots (128 KB), counted vmcnt(8)
// pipeline, cross-tile REGISTER pipelining (frags of tile T+1 ds_read during
// tile T's MFMA cluster; ping-pong frag sets, statically indexed), swizzled
// LDS via pre-swizzled global source (0 bank conflicts), XCD swizzle, setprio.

#define D_MODEL 1024
#define D_FF    4096
#define NTOK    4096
#define NC      9
#define K1      (D_MODEL * NC)  // 9216
#define K3      (D_FF * NC)     // 36864
#define SPLITK2 16
#define CHUNK   1024

typedef __attribute__((ext_vector_type(8))) short bf16x8;
typedef __attribute__((ext_vector_type(4))) float f32x4;

__device__ __forceinline__ unsigned short bf16b(float f) {
  __hip_bfloat16 h = __float2bfloat16(f);
  return __builtin_bit_cast(unsigned short, h);
}

// ---------------------------------------------------------------------------
// silu + 8 cubic B-spline bases on uniform grid t_m = 0.4*m - 2.2
// ---------------------------------------------------------------------------
__device__ __forceinline__ void kan_feat_u(float x, unsigned short* dst) {
  float s = x / (1.0f + __expf(-x));
  float B[11];
#pragma unroll
  for (int j = 0; j < 11; ++j) {
    float gj = -2.2f + 0.4f * j;
    B[j] = (x >= gj && x < gj + 0.4f) ? 1.0f : 0.0f;
  }
#pragma unroll
  for (int p = 1; p <= 3; ++p) {
    float inv = 1.0f / (0.4f * p);
#pragma unroll
    for (int i = 0; i + p < 11; ++i) {
      float gi = -2.2f + 0.4f * i;
      B[i] = (x - gi) * inv * B[i] + ((gi + 0.4f + 0.4f * p) - x) * inv * B[i + 1];
    }
  }
  dst[0] = bf16b(s);
#pragma unroll
  for (int c = 0; c < 8; ++c) dst[1 + c] = bf16b(B[c]);
}

// ---------------------------------------------------------------------------
// Pack two adjacent input-features per thread -> 9 dword stores (coalesced).
// ---------------------------------------------------------------------------
__global__ void pack_kan_w(const float* __restrict__ bw, const float* __restrict__ sw,
                           __hip_bfloat16* __restrict__ W, int K, int inShift,
                           size_t oBase, size_t totalPairs) {
  size_t t = (size_t)blockIdx.x * blockDim.x + threadIdx.x;
  if (t >= totalPairs) return;
  size_t o = t >> (inShift - 1);
  size_t ip = (t & (((size_t)1 << (inShift - 1)) - 1)) * 2;
  size_t e0 = (o << inShift) + ip;
  float2 b = *(const float2*)(bw + e0);
  const float4* sp = (const float4*)(sw + e0 * 8);
  float4 s0 = sp[0], s1 = sp[1], s2 = sp[2], s3 = sp[3];
  unsigned short h[18];
  h[0] = bf16b(b.x);
  h[1] = bf16b(s0.x); h[2] = bf16b(s0.y); h[3] = bf16b(s0.z); h[4] = bf16b(s0.w);
  h[5] = bf16b(s1.x); h[6] = bf16b(s1.y); h[7] = bf16b(s1.z); h[8] = bf16b(s1.w);
  h[9] = bf16b(b.y);
  h[10] = bf16b(s2.x); h[11] = bf16b(s2.y); h[12] = bf16b(s2.z); h[13] = bf16b(s2.w);
  h[14] = bf16b(s3.x); h[15] = bf16b(s3.y); h[16] = bf16b(s3.z); h[17] = bf16b(s3.w);
  uint32_t* dst = (uint32_t*)(W + (oBase + o) * (size_t)K + ip * NC);
#pragma unroll
  for (int k = 0; k < 9; ++k) dst[k] = (uint32_t)h[2 * k] | ((uint32_t)h[2 * k + 1] << 16);
}

// A1 from x; two elements per thread
__global__ void build_a1(const float* __restrict__ x, __hip_bfloat16* __restrict__ A1) {
  size_t t = (size_t)blockIdx.x * blockDim.x + threadIdx.x;
  if (t >= (size_t)NTOK * D_MODEL / 2) return;
  size_t n = t >> 9;
  size_t ip = (t & 511) * 2;
  float2 xv = *(const float2*)(x + n * D_MODEL + ip);
  unsigned short h[18];
  kan_feat_u(xv.x, h);
  kan_feat_u(xv.y, h + 9);
  uint32_t* dst = (uint32_t*)(A1 + n * (size_t)K1 + ip * NC);
#pragma unroll
  for (int k = 0; k < 9; ++k) dst[k] = (uint32_t)h[2 * k] | ((uint32_t)h[2 * k + 1] << 16);
}

// h = Hc[:, :4096] * Hc[:, 4096:]; two j per thread
template <typename HT>
__global__ void glu_a3(const HT* __restrict__ Hc, __hip_bfloat16* __restrict__ A3c) {
  size_t t = (size_t)blockIdx.x * blockDim.x + threadIdx.x;
  if (t >= (size_t)CHUNK * D_FF / 2) return;
  size_t n = t >> 11;
  size_t jp = (t & 2047) * 2;
  float a0, a1, c0, c1;
  if constexpr (std::is_same<HT, float>::value) {
    float2 u = *(const float2*)(Hc + n * 8192 + jp);
    float2 v = *(const float2*)(Hc + n * 8192 + 4096 + jp);
    a0 = u.x; a1 = u.y; c0 = v.x; c1 = v.y;
  } else {
    a0 = __bfloat162float(Hc[n * 8192 + jp]);
    a1 = __bfloat162float(Hc[n * 8192 + jp + 1]);
    c0 = __bfloat162float(Hc[n * 8192 + 4096 + jp]);
    c1 = __bfloat162float(Hc[n * 8192 + 4096 + jp + 1]);
  }
  unsigned short h[18];
  kan_feat_u(a0 * c0, h);
  kan_feat_u(a1 * c1, h + 9);
  uint32_t* dst = (uint32_t*)(A3c + n * (size_t)K3 + jp * NC);
#pragma unroll
  for (int k = 0; k < 9; ++k) dst[k] = (uint32_t)h[2 * k] | ((uint32_t)h[2 * k + 1] << 16);
}

// ---------------------------------------------------------------------------
// 256x256 bf16 GEMM, ring-4 + cross-tile register pipeline.
// Per iter T: STAGE(T+3); vmcnt(8) [tile T+1 landed]; barrier#1;
//   ds_read frags(T+1) [no wait]; 32 MFMA on frags(T) [hides the reads];
//   lgkmcnt(0) [~free]; barrier#2.
// Slot safety: STAGE(T+3) writes slot (T-1)%4, whose ds_reads drained before
// iter T-2's barrier#2 (lgkmcnt(0) precedes it).
// ---------------------------------------------------------------------------
#define STAGE(Ts)                                                                        \
  {                                                                                      \
    const int _sl = ((Ts) & 3) * 32768;                                                  \
    const size_t _ko = (size_t)(Ts) * 64;                                                \
    __builtin_amdgcn_global_load_lds(                                                    \
        (const __attribute__((address_space(1))) void*)(gA0 + _ko),                      \
        (__attribute__((address_space(3))) void*)(lds_raw + _sl + dA0), 16, 0, 0);       \
    __builtin_amdgcn_global_load_lds(                                                    \
        (const __attribute__((address_space(1))) void*)(gA1 + _ko),                      \
        (__attribute__((address_space(3))) void*)(lds_raw + _sl + dA1), 16, 0, 0);       \
    __builtin_amdgcn_global_load_lds(                                                    \
        (const __attribute__((address_space(1))) void*)(gB0 + _ko),                      \
        (__attribute__((address_space(3))) void*)(lds_raw + _sl + dB0), 16, 0, 0);       \
    __builtin_amdgcn_global_load_lds(                                                    \
        (const __attribute__((address_space(1))) void*)(gB1 + _ko),                      \
        (__attribute__((address_space(3))) void*)(lds_raw + _sl + dB1), 16, 0, 0);       \
  }

#define READ_FRAGS(Ts, AF, BF)                                                           \
  {                                                                                      \
    const int _sr = ((Ts) & 3) * 32768;                                                  \
    _Pragma("unroll") for (int _mf = 0; _mf < 8; ++_mf)                                  \
        AF[_mf] = *(const bf16x8*)(lds_raw + _sr + aoff + _mf * 1024);                   \
    _Pragma("unroll") for (int _nf = 0; _nf < 4; ++_nf)                                  \
        BF[_nf] = *(const bf16x8*)(lds_raw + _sr + boff + _nf * 1024);                   \
  }

#define TILE_BODY(T, AC, BC, AN, BN)                                                     \
  {                                                                                      \
    if ((T) + 3 < NT) STAGE((T) + 3);                                                    \
    if ((T) + 3 < NT) {                                                                  \
      asm volatile("s_waitcnt vmcnt(8)" ::: "memory");                                   \
    } else if ((T) + 3 == NT) {                                                          \
      asm volatile("s_waitcnt vmcnt(4)" ::: "memory");                                   \
    } else if ((T) + 2 == NT) {                                                          \
      asm volatile("s_waitcnt vmcnt(0)" ::: "memory");                                   \
    }                                                                                    \
    __builtin_amdgcn_s_barrier(); /* tile T+1 landed globally */                         \
    if ((T) + 1 < NT) READ_FRAGS((T) + 1, AN, BN);                                       \
    __builtin_amdgcn_s_setprio(1);                                                       \
    _Pragma("unroll") for (int _m = 0; _m < 8; ++_m)                                     \
        _Pragma("unroll") for (int _n = 0; _n < 4; ++_n)                                 \
            acc[_m][_n] = __builtin_amdgcn_mfma_f32_16x16x32_bf16(                       \
                AC[_m], BC[_n], acc[_m][_n], 0, 0, 0);                                   \
    __builtin_amdgcn_s_setprio(0);                                                       \
    asm volatile("s_waitcnt lgkmcnt(0)" ::: "memory"); /* free: hidden by MFMA */        \
    __builtin_amdgcn_s_barrier();                                                        \
  }

template <typename CT>
__global__ __launch_bounds__(512, 2) void gemm256(
    const __hip_bfloat16* __restrict__ A, const __hip_bfloat16* __restrict__ Bw,
    CT* __restrict__ Cp, int N, int K, int kLen) {
  __shared__ __align__(16) char lds_raw[4 * 32768];  // 128 KB

  const int tid = threadIdx.x;
  const int wid = tid >> 6, lane = tid & 63;
  const int wr = wid >> 2, wc = wid & 3;

  // bijective XCD swizzle (T1); both grids have nwg % 8 == 0
  const int nwg = gridDim.x * gridDim.y;
  const int orig = blockIdx.y * gridDim.x + blockIdx.x;
  const int q = nwg >> 3, r = nwg & 7;
  const int xcd = orig & 7, lid = orig >> 3;
  const int wg = (xcd < r ? xcd * (q + 1) : r * (q + 1) + (xcd - r) * q) + lid;
  const int bx = wg % gridDim.x, by = wg / gridDim.x;

  const size_t brow = (size_t)by * 256;
  const size_t bcol = (size_t)bx * 256;
  const int kStart = (int)blockIdx.z * kLen;
  const int NT = kLen / 32;  // even for all our shapes (288, 72)

  // staging: wave wid covers 16 rows of each half; 16B grp pre-swizzled
  const int kbx = (lane & 3) ^ ((lane >> 3) & 3);
  const int rsub = lane >> 2;
  const char* gA0 = (const char*)A +
      ((brow + (size_t)(wid * 16 + rsub)) * (size_t)K + kStart + kbx * 8) * 2;
  const char* gA1 = (const char*)A +
      ((brow + 128 + (size_t)(wid * 16 + rsub)) * (size_t)K + kStart + kbx * 8) * 2;
  const char* gB0 = (const char*)Bw +
      ((bcol + (size_t)(wid * 16 + rsub)) * (size_t)K + kStart + kbx * 8) * 2;
  const char* gB1 = (const char*)Bw +
      ((bcol + 128 + (size_t)(wid * 16 + rsub)) * (size_t)K + kStart + kbx * 8) * 2;
  const int dA0 = wid * 1024;
  const int dA1 = 8192 + wid * 1024;
  const int dB0 = 16384 + wid * 1024;
  const int dB1 = 24576 + wid * 1024;

  // ds_read fragment offsets (swizzled)
  const int fkb = (lane >> 4) ^ ((lane >> 1) & 3);
  const int aoff = (wr * 128 + (lane & 15)) * 64 + fkb * 16;
  const int boff = 16384 + (wc * 64 + (lane & 15)) * 64 + fkb * 16;

  f32x4 acc[8][4] = {};
  bf16x8 aP[8], bP[4], aQ[8], bQ[4];  // ping/pong frag sets (static indexing)

  // prologue: stage 0,1,2; tile0 landed globally; read frags(0) into ping
  STAGE(0);
  STAGE(1);
  STAGE(2);
  asm volatile("s_waitcnt vmcnt(8)" ::: "memory");
  __builtin_amdgcn_s_barrier();
  READ_FRAGS(0, aP, bP);

  for (int T = 0; T < NT; T += 2) {
    TILE_BODY(T, aP, bP, aQ, bQ);
    TILE_BODY(T + 1, aQ, bQ, aP, bP);
  }

  // epilogue: C/D layout col=lane&15, row=(lane>>4)*4+r
#pragma unroll
  for (int mf = 0; mf < 8; ++mf)
#pragma unroll
    for (int nf = 0; nf < 4; ++nf) {
      const size_t r0 = brow + wr * 128 + mf * 16 + (lane >> 4) * 4;
      const size_t c0 = bcol + wc * 64 + nf * 16 + (lane & 15);
      const size_t M = (size_t)gridDim.y * 256;
      CT* C = Cp + (size_t)blockIdx.z * M * (size_t)N;
#pragma unroll
      for (int rr = 0; rr < 4; ++rr) {
        float v = acc[mf][nf][rr];
        if constexpr (std::is_same<CT, float>::value)
          C[(r0 + rr) * (size_t)N + c0] = v;
        else
          C[(r0 + rr) * (size_t)N + c0] = __float2bfloat16(v);
      }
    }
}

// sum SPLITK2 split-K partials (float4-vectorized)
__global__ void reduceK(const float* __restrict__ P, float* __restrict__ out, size_t quarter) {
  size_t t = (size_t)blockIdx.x * blockDim.x + threadIdx.x;
  if (t >= quarter) return;
  const float4* p = (const float4*)P;
  float4 a = p[t];
#pragma unroll
  for (int s = 1; s < SPLITK2; ++s) {
    float4 b = p[(size_t)s * quarter + t];
    a.x += b.x; a.y += b.y; a.z += b.z; a.w += b.w;
  }
  ((float4*)out)[t] = a;
}

// ---------------------------------------------------------------------------
extern "C" void kernel_launch(void* const* d_in, const int* in_sizes, int n_in,
                              void* d_out, int out_size, void* d_ws, size_t ws_size,
                              hipStream_t stream) {
  const float* x   = (const float*)d_in[0];
  const float* bw1 = (const float*)d_in[1];
  const float* sw1 = (const float*)d_in[2];
  const float* bw2 = (const float*)d_in[3];
  const float* sw2 = (const float*)d_in[4];
  const float* bw3 = (const float*)d_in[5];
  const float* sw3 = (const float*)d_in[6];
  float* out = (float*)d_out;
  char* ws = (char*)d_ws;

  const size_t W12_B  = (size_t)8192 * K1 * 2;   // 150,994,944
  const size_t A1_B   = (size_t)NTOK * K1 * 2;   //  75,497,472
  const size_t A3C_B  = (size_t)CHUNK * K3 * 2;  //  75,497,472
  const size_t HF32_B = (size_t)NTOK * 8192 * 4; // 134,217,728

  const bool hF32 = ws_size >= W12_B + A1_B + HF32_B;  // 360,710,144

  __hip_bfloat16* W12 = (__hip_bfloat16*)(ws);
  __hip_bfloat16* A1  = (__hip_bfloat16*)(ws + W12_B);
  __hip_bfloat16* W3  = A1;                              // A1 dead after GEMM1
  void*           Hv  = (void*)(ws + W12_B + A1_B);
  __hip_bfloat16* A3c = (__hip_bfloat16*)(ws);           // W12 dead after GEMM1
  float*          Par = (float*)(ws + A3C_B);            // 16x1024x1024 f32

  // 1) pack W12
  {
    size_t pairs = (size_t)D_FF * D_MODEL / 2;
    int blocks = (int)((pairs + 255) / 256);
    pack_kan_w<<<blocks, 256, 0, stream>>>(bw1, sw1, W12, K1, 10, 0, pairs);
    pack_kan_w<<<blocks, 256, 0, stream>>>(bw2, sw2, W12, K1, 10, 4096, pairs);
  }
  // 2) build A1
  {
    size_t pairs = (size_t)NTOK * D_MODEL / 2;
    build_a1<<<(int)((pairs + 255) / 256), 256, 0, stream>>>(x, A1);
  }
  // 3) GEMM1: (4096 x 9216) x (8192 x 9216)^T -> H
  if (hF32)
    gemm256<float><<<dim3(8192 / 256, NTOK / 256, 1), 512, 0, stream>>>(
        A1, W12, (float*)Hv, 8192, K1, K1);
  else
    gemm256<__hip_bfloat16><<<dim3(8192 / 256, NTOK / 256, 1), 512, 0, stream>>>(
        A1, W12, (__hip_bfloat16*)Hv, 8192, K1, K1);
  // 4) pack W3 (into A1's region)
  {
    size_t pairs = (size_t)D_MODEL * D_FF / 2;
    pack_kan_w<<<(int)((pairs + 255) / 256), 256, 0, stream>>>(bw3, sw3, W3, K3, 12, 0, pairs);
  }
  // 5) per-chunk: GLU+A3 build, GEMM2 split-K=16, reduce
  for (int c = 0; c < NTOK / CHUNK; ++c) {
    {
      size_t pairs = (size_t)CHUNK * D_FF / 2;
      int blocks = (int)((pairs + 255) / 256);
      if (hF32)
        glu_a3<float><<<blocks, 256, 0, stream>>>(
            (const float*)Hv + (size_t)c * CHUNK * 8192, A3c);
      else
        glu_a3<__hip_bfloat16><<<blocks, 256, 0, stream>>>(
            (const __hip_bfloat16*)Hv + (size_t)c * CHUNK * 8192, A3c);
    }
    gemm256<float><<<dim3(D_MODEL / 256, CHUNK / 256, SPLITK2), 512, 0, stream>>>(
        A3c, W3, Par, D_MODEL, K3, K3 / SPLITK2);
    {
      size_t quarter = (size_t)CHUNK * D_MODEL / 4;
      reduceK<<<(int)((quarter + 255) / 256), 256, 0, stream>>>(
          Par, out + (size_t)c * CHUNK * D_MODEL, quarter);
    }
  }
}

// Round 6
// 1220.431 us; speedup vs baseline: 1.0005x; 1.0005x over previous
//
#include <hip/hip_runtime.h>
#include <hip/hip_bf16.h>
#include <cstdint>
#include <cstddef>
#include <type_traits>

// KAN GLU expert: h = kan(x;w1) * kan(x;w2); out = kan(h;w3)
// kan(x;W) == [silu(x_i), B0..B7(x_i)]_i @ [base_w | spline_w]^T
// -> bf16 MFMA GEMMs with K expanded 9x.
//
// GEMM: 256x256 tile, BK=32, ring-4 LDS slots (128 KB), counted vmcnt(8)
// pipeline, cross-tile REGISTER pipelining: frags of tile T+1 ds_read before
// tile T's MFMA cluster, pinned there with sched_barrier(0) so the MFMA
// cluster (register-only) co-issues while the reads drain on the LDS pipe.

#define D_MODEL 1024
#define D_FF    4096
#define NTOK    4096
#define NC      9
#define K1      (D_MODEL * NC)  // 9216
#define K3      (D_FF * NC)     // 36864
#define SPLITK2 16
#define CHUNK   1024

typedef __attribute__((ext_vector_type(8))) short bf16x8;
typedef __attribute__((ext_vector_type(4))) float f32x4;

__device__ __forceinline__ unsigned short bf16b(float f) {
  __hip_bfloat16 h = __float2bfloat16(f);
  return __builtin_bit_cast(unsigned short, h);
}

// ---------------------------------------------------------------------------
// silu + 8 cubic B-spline bases on uniform grid t_m = 0.4*m - 2.2
// ---------------------------------------------------------------------------
__device__ __forceinline__ void kan_feat_u(float x, unsigned short* dst) {
  float s = x / (1.0f + __expf(-x));
  float B[11];
#pragma unroll
  for (int j = 0; j < 11; ++j) {
    float gj = -2.2f + 0.4f * j;
    B[j] = (x >= gj && x < gj + 0.4f) ? 1.0f : 0.0f;
  }
#pragma unroll
  for (int p = 1; p <= 3; ++p) {
    float inv = 1.0f / (0.4f * p);
#pragma unroll
    for (int i = 0; i + p < 11; ++i) {
      float gi = -2.2f + 0.4f * i;
      B[i] = (x - gi) * inv * B[i] + ((gi + 0.4f + 0.4f * p) - x) * inv * B[i + 1];
    }
  }
  dst[0] = bf16b(s);
#pragma unroll
  for (int c = 0; c < 8; ++c) dst[1 + c] = bf16b(B[c]);
}

// ---------------------------------------------------------------------------
// Pack two adjacent input-features per thread -> 9 dword stores (coalesced).
// ---------------------------------------------------------------------------
__global__ void pack_kan_w(const float* __restrict__ bw, const float* __restrict__ sw,
                           __hip_bfloat16* __restrict__ W, int K, int inShift,
                           size_t oBase, size_t totalPairs) {
  size_t t = (size_t)blockIdx.x * blockDim.x + threadIdx.x;
  if (t >= totalPairs) return;
  size_t o = t >> (inShift - 1);
  size_t ip = (t & (((size_t)1 << (inShift - 1)) - 1)) * 2;
  size_t e0 = (o << inShift) + ip;
  float2 b = *(const float2*)(bw + e0);
  const float4* sp = (const float4*)(sw + e0 * 8);
  float4 s0 = sp[0], s1 = sp[1], s2 = sp[2], s3 = sp[3];
  unsigned short h[18];
  h[0] = bf16b(b.x);
  h[1] = bf16b(s0.x); h[2] = bf16b(s0.y); h[3] = bf16b(s0.z); h[4] = bf16b(s0.w);
  h[5] = bf16b(s1.x); h[6] = bf16b(s1.y); h[7] = bf16b(s1.z); h[8] = bf16b(s1.w);
  h[9] = bf16b(b.y);
  h[10] = bf16b(s2.x); h[11] = bf16b(s2.y); h[12] = bf16b(s2.z); h[13] = bf16b(s2.w);
  h[14] = bf16b(s3.x); h[15] = bf16b(s3.y); h[16] = bf16b(s3.z); h[17] = bf16b(s3.w);
  uint32_t* dst = (uint32_t*)(W + (oBase + o) * (size_t)K + ip * NC);
#pragma unroll
  for (int k = 0; k < 9; ++k) dst[k] = (uint32_t)h[2 * k] | ((uint32_t)h[2 * k + 1] << 16);
}

// A1 from x; two elements per thread
__global__ void build_a1(const float* __restrict__ x, __hip_bfloat16* __restrict__ A1) {
  size_t t = (size_t)blockIdx.x * blockDim.x + threadIdx.x;
  if (t >= (size_t)NTOK * D_MODEL / 2) return;
  size_t n = t >> 9;
  size_t ip = (t & 511) * 2;
  float2 xv = *(const float2*)(x + n * D_MODEL + ip);
  unsigned short h[18];
  kan_feat_u(xv.x, h);
  kan_feat_u(xv.y, h + 9);
  uint32_t* dst = (uint32_t*)(A1 + n * (size_t)K1 + ip * NC);
#pragma unroll
  for (int k = 0; k < 9; ++k) dst[k] = (uint32_t)h[2 * k] | ((uint32_t)h[2 * k + 1] << 16);
}

// h = Hc[:, :4096] * Hc[:, 4096:]; two j per thread
template <typename HT>
__global__ void glu_a3(const HT* __restrict__ Hc, __hip_bfloat16* __restrict__ A3c) {
  size_t t = (size_t)blockIdx.x * blockDim.x + threadIdx.x;
  if (t >= (size_t)CHUNK * D_FF / 2) return;
  size_t n = t >> 11;
  size_t jp = (t & 2047) * 2;
  float a0, a1, c0, c1;
  if constexpr (std::is_same<HT, float>::value) {
    float2 u = *(const float2*)(Hc + n * 8192 + jp);
    float2 v = *(const float2*)(Hc + n * 8192 + 4096 + jp);
    a0 = u.x; a1 = u.y; c0 = v.x; c1 = v.y;
  } else {
    a0 = __bfloat162float(Hc[n * 8192 + jp]);
    a1 = __bfloat162float(Hc[n * 8192 + jp + 1]);
    c0 = __bfloat162float(Hc[n * 8192 + 4096 + jp]);
    c1 = __bfloat162float(Hc[n * 8192 + 4096 + jp + 1]);
  }
  unsigned short h[18];
  kan_feat_u(a0 * c0, h);
  kan_feat_u(a1 * c1, h + 9);
  uint32_t* dst = (uint32_t*)(A3c + n * (size_t)K3 + jp * NC);
#pragma unroll
  for (int k = 0; k < 9; ++k) dst[k] = (uint32_t)h[2 * k] | ((uint32_t)h[2 * k + 1] << 16);
}

// ---------------------------------------------------------------------------
// 256x256 bf16 GEMM, ring-4 + cross-tile register pipeline.
// Per iter T: STAGE(T+3); vmcnt(8) [tile T+1 landed]; barrier#1;
//   ds_read frags(T+1); sched_barrier(0)  <- pin reads ABOVE the MFMAs;
//   32 MFMA on frags(T) [already in regs -> co-issue with draining reads];
//   lgkmcnt(0) [~free]; barrier#2.
// Slot safety: STAGE(T+3) writes slot (T-1)%4, whose ds_reads drained before
// iter T-2's barrier#2 (lgkmcnt(0) precedes it).
// ---------------------------------------------------------------------------
#define STAGE(Ts)                                                                        \
  {                                                                                      \
    const int _sl = ((Ts) & 3) * 32768;                                                  \
    const size_t _ko = (size_t)(Ts) * 64;                                                \
    __builtin_amdgcn_global_load_lds(                                                    \
        (const __attribute__((address_space(1))) void*)(gA0 + _ko),                      \
        (__attribute__((address_space(3))) void*)(lds_raw + _sl + dA0), 16, 0, 0);       \
    __builtin_amdgcn_global_load_lds(                                                    \
        (const __attribute__((address_space(1))) void*)(gA1 + _ko),                      \
        (__attribute__((address_space(3))) void*)(lds_raw + _sl + dA1), 16, 0, 0);       \
    __builtin_amdgcn_global_load_lds(                                                    \
        (const __attribute__((address_space(1))) void*)(gB0 + _ko),                      \
        (__attribute__((address_space(3))) void*)(lds_raw + _sl + dB0), 16, 0, 0);       \
    __builtin_amdgcn_global_load_lds(                                                    \
        (const __attribute__((address_space(1))) void*)(gB1 + _ko),                      \
        (__attribute__((address_space(3))) void*)(lds_raw + _sl + dB1), 16, 0, 0);       \
  }

#define READ_FRAGS(Ts, AF, BF)                                                           \
  {                                                                                      \
    const int _sr = ((Ts) & 3) * 32768;                                                  \
    _Pragma("unroll") for (int _mf = 0; _mf < 8; ++_mf)                                  \
        AF[_mf] = *(const bf16x8*)(lds_raw + _sr + aoff + _mf * 1024);                   \
    _Pragma("unroll") for (int _nf = 0; _nf < 4; ++_nf)                                  \
        BF[_nf] = *(const bf16x8*)(lds_raw + _sr + boff + _nf * 1024);                   \
  }

#define TILE_BODY(T, AC, BC, AN, BN)                                                     \
  {                                                                                      \
    if ((T) + 3 < NT) STAGE((T) + 3);                                                    \
    if ((T) + 3 < NT) {                                                                  \
      asm volatile("s_waitcnt vmcnt(8)" ::: "memory");                                   \
    } else if ((T) + 3 == NT) {                                                          \
      asm volatile("s_waitcnt vmcnt(4)" ::: "memory");                                   \
    } else if ((T) + 2 == NT) {                                                          \
      asm volatile("s_waitcnt vmcnt(0)" ::: "memory");                                   \
    }                                                                                    \
    __builtin_amdgcn_s_barrier(); /* tile T+1 landed globally */                         \
    if ((T) + 1 < NT) READ_FRAGS((T) + 1, AN, BN);                                       \
    __builtin_amdgcn_sched_barrier(0); /* pin: ds_reads above, MFMAs below */            \
    __builtin_amdgcn_s_setprio(1);                                                       \
    _Pragma("unroll") for (int _m = 0; _m < 8; ++_m)                                     \
        _Pragma("unroll") for (int _n = 0; _n < 4; ++_n)                                 \
            acc[_m][_n] = __builtin_amdgcn_mfma_f32_16x16x32_bf16(                       \
                AC[_m], BC[_n], acc[_m][_n], 0, 0, 0);                                   \
    __builtin_amdgcn_s_setprio(0);                                                       \
    asm volatile("s_waitcnt lgkmcnt(0)" ::: "memory"); /* free: hidden by MFMA */        \
    __builtin_amdgcn_s_barrier();                                                        \
  }

template <typename CT>
__global__ __launch_bounds__(512, 2) void gemm256(
    const __hip_bfloat16* __restrict__ A, const __hip_bfloat16* __restrict__ Bw,
    CT* __restrict__ Cp, int N, int K, int kLen) {
  __shared__ __align__(16) char lds_raw[4 * 32768];  // 128 KB

  const int tid = threadIdx.x;
  const int wid = tid >> 6, lane = tid & 63;
  const int wr = wid >> 2, wc = wid & 3;

  // bijective XCD swizzle (T1); both grids have nwg % 8 == 0
  const int nwg = gridDim.x * gridDim.y;
  const int orig = blockIdx.y * gridDim.x + blockIdx.x;
  const int q = nwg >> 3, r = nwg & 7;
  const int xcd = orig & 7, lid = orig >> 3;
  const int wg = (xcd < r ? xcd * (q + 1) : r * (q + 1) + (xcd - r) * q) + lid;
  const int bx = wg % gridDim.x, by = wg / gridDim.x;

  const size_t brow = (size_t)by * 256;
  const size_t bcol = (size_t)bx * 256;
  const int kStart = (int)blockIdx.z * kLen;
  const int NT = kLen / 32;  // even for all our shapes (288, 72)

  // staging: wave wid covers 16 rows of each half; 16B grp pre-swizzled
  const int kbx = (lane & 3) ^ ((lane >> 3) & 3);
  const int rsub = lane >> 2;
  const char* gA0 = (const char*)A +
      ((brow + (size_t)(wid * 16 + rsub)) * (size_t)K + kStart + kbx * 8) * 2;
  const char* gA1 = (const char*)A +
      ((brow + 128 + (size_t)(wid * 16 + rsub)) * (size_t)K + kStart + kbx * 8) * 2;
  const char* gB0 = (const char*)Bw +
      ((bcol + (size_t)(wid * 16 + rsub)) * (size_t)K + kStart + kbx * 8) * 2;
  const char* gB1 = (const char*)Bw +
      ((bcol + 128 + (size_t)(wid * 16 + rsub)) * (size_t)K + kStart + kbx * 8) * 2;
  const int dA0 = wid * 1024;
  const int dA1 = 8192 + wid * 1024;
  const int dB0 = 16384 + wid * 1024;
  const int dB1 = 24576 + wid * 1024;

  // ds_read fragment offsets (swizzled)
  const int fkb = (lane >> 4) ^ ((lane >> 1) & 3);
  const int aoff = (wr * 128 + (lane & 15)) * 64 + fkb * 16;
  const int boff = 16384 + (wc * 64 + (lane & 15)) * 64 + fkb * 16;

  f32x4 acc[8][4] = {};
  bf16x8 aP[8], bP[4], aQ[8], bQ[4];  // ping/pong frag sets (static indexing)

  // prologue: stage 0,1,2; tile0 landed globally; read frags(0) into ping
  STAGE(0);
  STAGE(1);
  STAGE(2);
  asm volatile("s_waitcnt vmcnt(8)" ::: "memory");
  __builtin_amdgcn_s_barrier();
  READ_FRAGS(0, aP, bP);

  for (int T = 0; T < NT; T += 2) {
    TILE_BODY(T, aP, bP, aQ, bQ);
    TILE_BODY(T + 1, aQ, bQ, aP, bP);
  }

  // epilogue: C/D layout col=lane&15, row=(lane>>4)*4+r
#pragma unroll
  for (int mf = 0; mf < 8; ++mf)
#pragma unroll
    for (int nf = 0; nf < 4; ++nf) {
      const size_t r0 = brow + wr * 128 + mf * 16 + (lane >> 4) * 4;
      const size_t c0 = bcol + wc * 64 + nf * 16 + (lane & 15);
      const size_t M = (size_t)gridDim.y * 256;
      CT* C = Cp + (size_t)blockIdx.z * M * (size_t)N;
#pragma unroll
      for (int rr = 0; rr < 4; ++rr) {
        float v = acc[mf][nf][rr];
        if constexpr (std::is_same<CT, float>::value)
          C[(r0 + rr) * (size_t)N + c0] = v;
        else
          C[(r0 + rr) * (size_t)N + c0] = __float2bfloat16(v);
      }
    }
}

// sum SPLITK2 split-K partials (float4-vectorized)
__global__ void reduceK(const float* __restrict__ P, float* __restrict__ out, size_t quarter) {
  size_t t = (size_t)blockIdx.x * blockDim.x + threadIdx.x;
  if (t >= quarter) return;
  const float4* p = (const float4*)P;
  float4 a = p[t];
#pragma unroll
  for (int s = 1; s < SPLITK2; ++s) {
    float4 b = p[(size_t)s * quarter + t];
    a.x += b.x; a.y += b.y; a.z += b.z; a.w += b.w;
  }
  ((float4*)out)[t] = a;
}

// ---------------------------------------------------------------------------
extern "C" void kernel_launch(void* const* d_in, const int* in_sizes, int n_in,
                              void* d_out, int out_size, void* d_ws, size_t ws_size,
                              hipStream_t stream) {
  const float* x   = (const float*)d_in[0];
  const float* bw1 = (const float*)d_in[1];
  const float* sw1 = (const float*)d_in[2];
  const float* bw2 = (const float*)d_in[3];
  const float* sw2 = (const float*)d_in[4];
  const float* bw3 = (const float*)d_in[5];
  const float* sw3 = (const float*)d_in[6];
  float* out = (float*)d_out;
  char* ws = (char*)d_ws;

  const size_t W12_B  = (size_t)8192 * K1 * 2;   // 150,994,944
  const size_t A1_B   = (size_t)NTOK * K1 * 2;   //  75,497,472
  const size_t A3C_B  = (size_t)CHUNK * K3 * 2;  //  75,497,472
  const size_t HF32_B = (size_t)NTOK * 8192 * 4; // 134,217,728

  const bool hF32 = ws_size >= W12_B + A1_B + HF32_B;  // 360,710,144

  __hip_bfloat16* W12 = (__hip_bfloat16*)(ws);
  __hip_bfloat16* A1  = (__hip_bfloat16*)(ws + W12_B);
  __hip_bfloat16* W3  = A1;                              // A1 dead after GEMM1
  void*           Hv  = (void*)(ws + W12_B + A1_B);
  __hip_bfloat16* A3c = (__hip_bfloat16*)(ws);           // W12 dead after GEMM1
  float*          Par = (float*)(ws + A3C_B);            // 16x1024x1024 f32

  // 1) pack W12
  {
    size_t pairs = (size_t)D_FF * D_MODEL / 2;
    int blocks = (int)((pairs + 255) / 256);
    pack_kan_w<<<blocks, 256, 0, stream>>>(bw1, sw1, W12, K1, 10, 0, pairs);
    pack_kan_w<<<blocks, 256, 0, stream>>>(bw2, sw2, W12, K1, 10, 4096, pairs);
  }
  // 2) build A1
  {
    size_t pairs = (size_t)NTOK * D_MODEL / 2;
    build_a1<<<(int)((pairs + 255) / 256), 256, 0, stream>>>(x, A1);
  }
  // 3) GEMM1: (4096 x 9216) x (8192 x 9216)^T -> H
  if (hF32)
    gemm256<float><<<dim3(8192 / 256, NTOK / 256, 1), 512, 0, stream>>>(
        A1, W12, (float*)Hv, 8192, K1, K1);
  else
    gemm256<__hip_bfloat16><<<dim3(8192 / 256, NTOK / 256, 1), 512, 0, stream>>>(
        A1, W12, (__hip_bfloat16*)Hv, 8192, K1, K1);
  // 4) pack W3 (into A1's region)
  {
    size_t pairs = (size_t)D_MODEL * D_FF / 2;
    pack_kan_w<<<(int)((pairs + 255) / 256), 256, 0, stream>>>(bw3, sw3, W3, K3, 12, 0, pairs);
  }
  // 5) per-chunk: GLU+A3 build, GEMM2 split-K=16, reduce
  for (int c = 0; c < NTOK / CHUNK; ++c) {
    {
      size_t pairs = (size_t)CHUNK * D_FF / 2;
      int blocks = (int)((pairs + 255) / 256);
      if (hF32)
        glu_a3<float><<<blocks, 256, 0, stream>>>(
            (const float*)Hv + (size_t)c * CHUNK * 8192, A3c);
      else
        glu_a3<__hip_bfloat16><<<blocks, 256, 0, stream>>>(
            (const __hip_bfloat16*)Hv + (size_t)c * CHUNK * 8192, A3c);
    }
    gemm256<float><<<dim3(D_MODEL / 256, CHUNK / 256, SPLITK2), 512, 0, stream>>>(
        A3c, W3, Par, D_MODEL, K3, K3 / SPLITK2);
    {
      size_t quarter = (size_t)CHUNK * D_MODEL / 4;
      reduceK<<<(int)((quarter + 255) / 256), 256, 0, stream>>>(
          Par, out + (size_t)c * CHUNK * D_MODEL, quarter);
    }
  }
}

// Round 7
// 1212.940 us; speedup vs baseline: 1.0067x; 1.0062x over previous
//
#include <hip/hip_runtime.h>
#include <hip/hip_bf16.h>
#include <cstdint>
#include <cstddef>
#include <type_traits>

// KAN GLU expert: h = kan(x;w1) * kan(x;w2); out = kan(h;w3)
// kan(x;W) == [silu(x_i), B0..B7(x_i)]_i @ [base_w | spline_w]^T
// -> bf16 MFMA GEMMs with K expanded 9x.
//
// GEMM: 256x256 tile, BK=32, ring-4 LDS slots (128 KB), counted vmcnt(8)
// pipeline, cross-tile register pipelining with FINE INTERLEAVE: the 12
// next-tile ds_read_b128 are issued in 4 bursts of 3 between 8-MFMA groups
// (sched_barrier-pinned) so the LDS request queue never saturates and the
// matrix pipe stays fed while reads drain.

#define D_MODEL 1024
#define D_FF    4096
#define NTOK    4096
#define NC      9
#define K1      (D_MODEL * NC)  // 9216
#define K3      (D_FF * NC)     // 36864
#define SPLITK2 16
#define CHUNK   1024

typedef __attribute__((ext_vector_type(8))) short bf16x8;
typedef __attribute__((ext_vector_type(4))) float f32x4;

__device__ __forceinline__ unsigned short bf16b(float f) {
  __hip_bfloat16 h = __float2bfloat16(f);
  return __builtin_bit_cast(unsigned short, h);
}

// ---------------------------------------------------------------------------
// silu + 8 cubic B-spline bases on uniform grid t_m = 0.4*m - 2.2
// ---------------------------------------------------------------------------
__device__ __forceinline__ void kan_feat_u(float x, unsigned short* dst) {
  float s = x / (1.0f + __expf(-x));
  float B[11];
#pragma unroll
  for (int j = 0; j < 11; ++j) {
    float gj = -2.2f + 0.4f * j;
    B[j] = (x >= gj && x < gj + 0.4f) ? 1.0f : 0.0f;
  }
#pragma unroll
  for (int p = 1; p <= 3; ++p) {
    float inv = 1.0f / (0.4f * p);
#pragma unroll
    for (int i = 0; i + p < 11; ++i) {
      float gi = -2.2f + 0.4f * i;
      B[i] = (x - gi) * inv * B[i] + ((gi + 0.4f + 0.4f * p) - x) * inv * B[i + 1];
    }
  }
  dst[0] = bf16b(s);
#pragma unroll
  for (int c = 0; c < 8; ++c) dst[1 + c] = bf16b(B[c]);
}

// ---------------------------------------------------------------------------
// Pack two adjacent input-features per thread -> 9 dword stores (coalesced).
// ---------------------------------------------------------------------------
__global__ void pack_kan_w(const float* __restrict__ bw, const float* __restrict__ sw,
                           __hip_bfloat16* __restrict__ W, int K, int inShift,
                           size_t oBase, size_t totalPairs) {
  size_t t = (size_t)blockIdx.x * blockDim.x + threadIdx.x;
  if (t >= totalPairs) return;
  size_t o = t >> (inShift - 1);
  size_t ip = (t & (((size_t)1 << (inShift - 1)) - 1)) * 2;
  size_t e0 = (o << inShift) + ip;
  float2 b = *(const float2*)(bw + e0);
  const float4* sp = (const float4*)(sw + e0 * 8);
  float4 s0 = sp[0], s1 = sp[1], s2 = sp[2], s3 = sp[3];
  unsigned short h[18];
  h[0] = bf16b(b.x);
  h[1] = bf16b(s0.x); h[2] = bf16b(s0.y); h[3] = bf16b(s0.z); h[4] = bf16b(s0.w);
  h[5] = bf16b(s1.x); h[6] = bf16b(s1.y); h[7] = bf16b(s1.z); h[8] = bf16b(s1.w);
  h[9] = bf16b(b.y);
  h[10] = bf16b(s2.x); h[11] = bf16b(s2.y); h[12] = bf16b(s2.z); h[13] = bf16b(s2.w);
  h[14] = bf16b(s3.x); h[15] = bf16b(s3.y); h[16] = bf16b(s3.z); h[17] = bf16b(s3.w);
  uint32_t* dst = (uint32_t*)(W + (oBase + o) * (size_t)K + ip * NC);
#pragma unroll
  for (int k = 0; k < 9; ++k) dst[k] = (uint32_t)h[2 * k] | ((uint32_t)h[2 * k + 1] << 16);
}

// A1 from x; two elements per thread
__global__ void build_a1(const float* __restrict__ x, __hip_bfloat16* __restrict__ A1) {
  size_t t = (size_t)blockIdx.x * blockDim.x + threadIdx.x;
  if (t >= (size_t)NTOK * D_MODEL / 2) return;
  size_t n = t >> 9;
  size_t ip = (t & 511) * 2;
  float2 xv = *(const float2*)(x + n * D_MODEL + ip);
  unsigned short h[18];
  kan_feat_u(xv.x, h);
  kan_feat_u(xv.y, h + 9);
  uint32_t* dst = (uint32_t*)(A1 + n * (size_t)K1 + ip * NC);
#pragma unroll
  for (int k = 0; k < 9; ++k) dst[k] = (uint32_t)h[2 * k] | ((uint32_t)h[2 * k + 1] << 16);
}

// h = Hc[:, :4096] * Hc[:, 4096:]; two j per thread
template <typename HT>
__global__ void glu_a3(const HT* __restrict__ Hc, __hip_bfloat16* __restrict__ A3c) {
  size_t t = (size_t)blockIdx.x * blockDim.x + threadIdx.x;
  if (t >= (size_t)CHUNK * D_FF / 2) return;
  size_t n = t >> 11;
  size_t jp = (t & 2047) * 2;
  float a0, a1, c0, c1;
  if constexpr (std::is_same<HT, float>::value) {
    float2 u = *(const float2*)(Hc + n * 8192 + jp);
    float2 v = *(const float2*)(Hc + n * 8192 + 4096 + jp);
    a0 = u.x; a1 = u.y; c0 = v.x; c1 = v.y;
  } else {
    a0 = __bfloat162float(Hc[n * 8192 + jp]);
    a1 = __bfloat162float(Hc[n * 8192 + jp + 1]);
    c0 = __bfloat162float(Hc[n * 8192 + 4096 + jp]);
    c1 = __bfloat162float(Hc[n * 8192 + 4096 + jp + 1]);
  }
  unsigned short h[18];
  kan_feat_u(a0 * c0, h);
  kan_feat_u(a1 * c1, h + 9);
  uint32_t* dst = (uint32_t*)(A3c + n * (size_t)K3 + jp * NC);
#pragma unroll
  for (int k = 0; k < 9; ++k) dst[k] = (uint32_t)h[2 * k] | ((uint32_t)h[2 * k + 1] << 16);
}

// ---------------------------------------------------------------------------
// 256x256 bf16 GEMM, ring-4 + cross-tile register pipeline, fine interleave.
// Per iter T: STAGE(T+3); vmcnt(8); barrier;
//   4x { 3 ds_read frags(T+1) ; SB ; 8 MFMA frags(T) ; SB }
//   lgkmcnt(0); barrier.
// Slot safety: STAGE(T+3) writes slot (T-1)%4, whose ds_reads drained before
// iter T-2's end barrier (lgkmcnt(0) precedes it).
// ---------------------------------------------------------------------------
#define STAGE(Ts)                                                                        \
  {                                                                                      \
    const int _sl = ((Ts) & 3) * 32768;                                                  \
    const size_t _ko = (size_t)(Ts) * 64;                                                \
    __builtin_amdgcn_global_load_lds(                                                    \
        (const __attribute__((address_space(1))) void*)(gA0 + _ko),                      \
        (__attribute__((address_space(3))) void*)(lds_raw + _sl + dA0), 16, 0, 0);       \
    __builtin_amdgcn_global_load_lds(                                                    \
        (const __attribute__((address_space(1))) void*)(gA1 + _ko),                      \
        (__attribute__((address_space(3))) void*)(lds_raw + _sl + dA1), 16, 0, 0);       \
    __builtin_amdgcn_global_load_lds(                                                    \
        (const __attribute__((address_space(1))) void*)(gB0 + _ko),                      \
        (__attribute__((address_space(3))) void*)(lds_raw + _sl + dB0), 16, 0, 0);       \
    __builtin_amdgcn_global_load_lds(                                                    \
        (const __attribute__((address_space(1))) void*)(gB1 + _ko),                      \
        (__attribute__((address_space(3))) void*)(lds_raw + _sl + dB1), 16, 0, 0);       \
  }

#define SB __builtin_amdgcn_sched_barrier(0)

// 8 MFMAs: rows m, m+1 of the current frag set against all 4 B frags
#define MFMA_PAIR(AC, BC, m)                                                             \
  _Pragma("unroll") for (int _n = 0; _n < 4; ++_n) {                                     \
    acc[m][_n] =                                                                         \
        __builtin_amdgcn_mfma_f32_16x16x32_bf16(AC[m], BC[_n], acc[m][_n], 0, 0, 0);     \
    acc[(m) + 1][_n] = __builtin_amdgcn_mfma_f32_16x16x32_bf16(AC[(m) + 1], BC[_n],      \
                                                               acc[(m) + 1][_n], 0, 0, 0);\
  }

#define TILE_BODY(T, AC, BC, AN, BN)                                                     \
  {                                                                                      \
    if ((T) + 3 < NT) STAGE((T) + 3);                                                    \
    if ((T) + 3 < NT) {                                                                  \
      asm volatile("s_waitcnt vmcnt(8)" ::: "memory");                                   \
    } else if ((T) + 3 == NT) {                                                          \
      asm volatile("s_waitcnt vmcnt(4)" ::: "memory");                                   \
    } else if ((T) + 2 == NT) {                                                          \
      asm volatile("s_waitcnt vmcnt(0)" ::: "memory");                                   \
    }                                                                                    \
    __builtin_amdgcn_s_barrier(); /* tile T+1 landed globally */                         \
    const int _sr = (((T) + 1) & 3) * 32768;                                             \
    const bool _rd = ((T) + 1 < NT);                                                     \
    __builtin_amdgcn_s_setprio(1);                                                       \
    if (_rd) {                                                                           \
      AN[0] = *(const bf16x8*)(lds_raw + _sr + aoff + 0 * 1024);                         \
      AN[1] = *(const bf16x8*)(lds_raw + _sr + aoff + 1 * 1024);                         \
      AN[2] = *(const bf16x8*)(lds_raw + _sr + aoff + 2 * 1024);                         \
    }                                                                                    \
    SB;                                                                                  \
    MFMA_PAIR(AC, BC, 0);                                                                \
    SB;                                                                                  \
    if (_rd) {                                                                           \
      AN[3] = *(const bf16x8*)(lds_raw + _sr + aoff + 3 * 1024);                         \
      AN[4] = *(const bf16x8*)(lds_raw + _sr + aoff + 4 * 1024);                         \
      AN[5] = *(const bf16x8*)(lds_raw + _sr + aoff + 5 * 1024);                         \
    }                                                                                    \
    SB;                                                                                  \
    MFMA_PAIR(AC, BC, 2);                                                                \
    SB;                                                                                  \
    if (_rd) {                                                                           \
      AN[6] = *(const bf16x8*)(lds_raw + _sr + aoff + 6 * 1024);                         \
      AN[7] = *(const bf16x8*)(lds_raw + _sr + aoff + 7 * 1024);                         \
      BN[0] = *(const bf16x8*)(lds_raw + _sr + boff + 0 * 1024);                         \
    }                                                                                    \
    SB;                                                                                  \
    MFMA_PAIR(AC, BC, 4);                                                                \
    SB;                                                                                  \
    if (_rd) {                                                                           \
      BN[1] = *(const bf16x8*)(lds_raw + _sr + boff + 1 * 1024);                         \
      BN[2] = *(const bf16x8*)(lds_raw + _sr + boff + 2 * 1024);                         \
      BN[3] = *(const bf16x8*)(lds_raw + _sr + boff + 3 * 1024);                         \
    }                                                                                    \
    SB;                                                                                  \
    MFMA_PAIR(AC, BC, 6);                                                                \
    __builtin_amdgcn_s_setprio(0);                                                       \
    asm volatile("s_waitcnt lgkmcnt(0)" ::: "memory");                                   \
    __builtin_amdgcn_s_barrier();                                                        \
  }

template <typename CT>
__global__ __launch_bounds__(512, 2) void gemm256(
    const __hip_bfloat16* __restrict__ A, const __hip_bfloat16* __restrict__ Bw,
    CT* __restrict__ Cp, int N, int K, int kLen) {
  __shared__ __align__(16) char lds_raw[4 * 32768];  // 128 KB

  const int tid = threadIdx.x;
  const int wid = tid >> 6, lane = tid & 63;
  const int wr = wid >> 2, wc = wid & 3;

  // bijective XCD swizzle (T1); both grids have nwg % 8 == 0
  const int nwg = gridDim.x * gridDim.y;
  const int orig = blockIdx.y * gridDim.x + blockIdx.x;
  const int q = nwg >> 3, r = nwg & 7;
  const int xcd = orig & 7, lid = orig >> 3;
  const int wg = (xcd < r ? xcd * (q + 1) : r * (q + 1) + (xcd - r) * q) + lid;
  const int bx = wg % gridDim.x, by = wg / gridDim.x;

  const size_t brow = (size_t)by * 256;
  const size_t bcol = (size_t)bx * 256;
  const int kStart = (int)blockIdx.z * kLen;
  const int NT = kLen / 32;  // even for all our shapes (288, 72)

  // staging: wave wid covers 16 rows of each half; 16B grp pre-swizzled
  const int kbx = (lane & 3) ^ ((lane >> 3) & 3);
  const int rsub = lane >> 2;
  const char* gA0 = (const char*)A +
      ((brow + (size_t)(wid * 16 + rsub)) * (size_t)K + kStart + kbx * 8) * 2;
  const char* gA1 = (const char*)A +
      ((brow + 128 + (size_t)(wid * 16 + rsub)) * (size_t)K + kStart + kbx * 8) * 2;
  const char* gB0 = (const char*)Bw +
      ((bcol + (size_t)(wid * 16 + rsub)) * (size_t)K + kStart + kbx * 8) * 2;
  const char* gB1 = (const char*)Bw +
      ((bcol + 128 + (size_t)(wid * 16 + rsub)) * (size_t)K + kStart + kbx * 8) * 2;
  const int dA0 = wid * 1024;
  const int dA1 = 8192 + wid * 1024;
  const int dB0 = 16384 + wid * 1024;
  const int dB1 = 24576 + wid * 1024;

  // ds_read fragment offsets (swizzled)
  const int fkb = (lane >> 4) ^ ((lane >> 1) & 3);
  const int aoff = (wr * 128 + (lane & 15)) * 64 + fkb * 16;
  const int boff = 16384 + (wc * 64 + (lane & 15)) * 64 + fkb * 16;

  f32x4 acc[8][4] = {};
  bf16x8 aP[8], bP[4], aQ[8], bQ[4];  // ping/pong frag sets (static indexing)

  // prologue: stage 0,1,2; tile0 landed globally; read frags(0) into ping
  STAGE(0);
  STAGE(1);
  STAGE(2);
  asm volatile("s_waitcnt vmcnt(8)" ::: "memory");
  __builtin_amdgcn_s_barrier();
#pragma unroll
  for (int mf = 0; mf < 8; ++mf)
    aP[mf] = *(const bf16x8*)(lds_raw + aoff + mf * 1024);
#pragma unroll
  for (int nf = 0; nf < 4; ++nf)
    bP[nf] = *(const bf16x8*)(lds_raw + boff + nf * 1024);

  for (int T = 0; T < NT; T += 2) {
    TILE_BODY(T, aP, bP, aQ, bQ);
    TILE_BODY(T + 1, aQ, bQ, aP, bP);
  }

  // epilogue: C/D layout col=lane&15, row=(lane>>4)*4+r
#pragma unroll
  for (int mf = 0; mf < 8; ++mf)
#pragma unroll
    for (int nf = 0; nf < 4; ++nf) {
      const size_t r0 = brow + wr * 128 + mf * 16 + (lane >> 4) * 4;
      const size_t c0 = bcol + wc * 64 + nf * 16 + (lane & 15);
      const size_t M = (size_t)gridDim.y * 256;
      CT* C = Cp + (size_t)blockIdx.z * M * (size_t)N;
#pragma unroll
      for (int rr = 0; rr < 4; ++rr) {
        float v = acc[mf][nf][rr];
        if constexpr (std::is_same<CT, float>::value)
          C[(r0 + rr) * (size_t)N + c0] = v;
        else
          C[(r0 + rr) * (size_t)N + c0] = __float2bfloat16(v);
      }
    }
}

// sum SPLITK2 split-K partials (float4-vectorized)
__global__ void reduceK(const float* __restrict__ P, float* __restrict__ out, size_t quarter) {
  size_t t = (size_t)blockIdx.x * blockDim.x + threadIdx.x;
  if (t >= quarter) return;
  const float4* p = (const float4*)P;
  float4 a = p[t];
#pragma unroll
  for (int s = 1; s < SPLITK2; ++s) {
    float4 b = p[(size_t)s * quarter + t];
    a.x += b.x; a.y += b.y; a.z += b.z; a.w += b.w;
  }
  ((float4*)out)[t] = a;
}

// ---------------------------------------------------------------------------
extern "C" void kernel_launch(void* const* d_in, const int* in_sizes, int n_in,
                              void* d_out, int out_size, void* d_ws, size_t ws_size,
                              hipStream_t stream) {
  const float* x   = (const float*)d_in[0];
  const float* bw1 = (const float*)d_in[1];
  const float* sw1 = (const float*)d_in[2];
  const float* bw2 = (const float*)d_in[3];
  const float* sw2 = (const float*)d_in[4];
  const float* bw3 = (const float*)d_in[5];
  const float* sw3 = (const float*)d_in[6];
  float* out = (float*)d_out;
  char* ws = (char*)d_ws;

  const size_t W12_B  = (size_t)8192 * K1 * 2;   // 150,994,944
  const size_t A1_B   = (size_t)NTOK * K1 * 2;   //  75,497,472
  const size_t A3C_B  = (size_t)CHUNK * K3 * 2;  //  75,497,472
  const size_t HF32_B = (size_t)NTOK * 8192 * 4; // 134,217,728

  const bool hF32 = ws_size >= W12_B + A1_B + HF32_B;  // 360,710,144

  __hip_bfloat16* W12 = (__hip_bfloat16*)(ws);
  __hip_bfloat16* A1  = (__hip_bfloat16*)(ws + W12_B);
  __hip_bfloat16* W3  = A1;                              // A1 dead after GEMM1
  void*           Hv  = (void*)(ws + W12_B + A1_B);
  __hip_bfloat16* A3c = (__hip_bfloat16*)(ws);           // W12 dead after GEMM1
  float*          Par = (float*)(ws + A3C_B);            // 16x1024x1024 f32

  // 1) pack W12
  {
    size_t pairs = (size_t)D_FF * D_MODEL / 2;
    int blocks = (int)((pairs + 255) / 256);
    pack_kan_w<<<blocks, 256, 0, stream>>>(bw1, sw1, W12, K1, 10, 0, pairs);
    pack_kan_w<<<blocks, 256, 0, stream>>>(bw2, sw2, W12, K1, 10, 4096, pairs);
  }
  // 2) build A1
  {
    size_t pairs = (size_t)NTOK * D_MODEL / 2;
    build_a1<<<(int)((pairs + 255) / 256), 256, 0, stream>>>(x, A1);
  }
  // 3) GEMM1: (4096 x 9216) x (8192 x 9216)^T -> H
  if (hF32)
    gemm256<float><<<dim3(8192 / 256, NTOK / 256, 1), 512, 0, stream>>>(
        A1, W12, (float*)Hv, 8192, K1, K1);
  else
    gemm256<__hip_bfloat16><<<dim3(8192 / 256, NTOK / 256, 1), 512, 0, stream>>>(
        A1, W12, (__hip_bfloat16*)Hv, 8192, K1, K1);
  // 4) pack W3 (into A1's region)
  {
    size_t pairs = (size_t)D_MODEL * D_FF / 2;
    pack_kan_w<<<(int)((pairs + 255) / 256), 256, 0, stream>>>(bw3, sw3, W3, K3, 12, 0, pairs);
  }
  // 5) per-chunk: GLU+A3 build, GEMM2 split-K=16, reduce
  for (int c = 0; c < NTOK / CHUNK; ++c) {
    {
      size_t pairs = (size_t)CHUNK * D_FF / 2;
      int blocks = (int)((pairs + 255) / 256);
      if (hF32)
        glu_a3<float><<<blocks, 256, 0, stream>>>(
            (const float*)Hv + (size_t)c * CHUNK * 8192, A3c);
      else
        glu_a3<__hip_bfloat16><<<blocks, 256, 0, stream>>>(
            (const __hip_bfloat16*)Hv + (size_t)c * CHUNK * 8192, A3c);
    }
    gemm256<float><<<dim3(D_MODEL / 256, CHUNK / 256, SPLITK2), 512, 0, stream>>>(
        A3c, W3, Par, D_MODEL, K3, K3 / SPLITK2);
    {
      size_t quarter = (size_t)CHUNK * D_MODEL / 4;
      reduceK<<<(int)((quarter + 255) / 256), 256, 0, stream>>>(
          Par, out + (size_t)c * CHUNK * D_MODEL, quarter);
    }
  }
}

// Round 8
// 1077.810 us; speedup vs baseline: 1.1329x; 1.1254x over previous
//
#include <hip/hip_runtime.h>
#include <hip/hip_bf16.h>
#include <cstdint>
#include <cstddef>
#include <type_traits>

// KAN GLU expert: h = kan(x;w1) * kan(x;w2); out = kan(h;w3)
// kan(x;W) == [silu(x_i), B0..B7(x_i)]_i @ [base_w | spline_w]^T
// -> bf16 MFMA GEMMs with K expanded 9x.
//
// Fused path (ws >= 528.5MB): W12 rows interleaved (2o=w1_o, 2o+1=w2_o);
// GEMM1 epilogue computes GLU pair-product via shfl_xor(1), pushes g through
// LDS transpose, generates 9 KAN features, writes A3 directly (no H).
// GEMM2 is then a single un-chunked dispatch with split-K=4.
// Fallback path (smaller ws): R7 flow (H + glu_a3 + chunked GEMM2).
// GEMM body: R3 structure (best measured) - ring-4 LDS slots, counted
// vmcnt(8), swizzled LDS via pre-swizzled global source, XCD swizzle.

#define D_MODEL 1024
#define D_FF    4096
#define NTOK    4096
#define NC      9
#define K1      (D_MODEL * NC)  // 9216
#define K3      (D_FF * NC)     // 36864
#define SPLITK2 16              // fallback chunked GEMM2
#define SPLITKF 4               // fused full GEMM2
#define CHUNK   1024

typedef __attribute__((ext_vector_type(8))) short bf16x8;
typedef __attribute__((ext_vector_type(4))) float f32x4;

__device__ __forceinline__ unsigned short bf16b(float f) {
  __hip_bfloat16 h = __float2bfloat16(f);
  return __builtin_bit_cast(unsigned short, h);
}

// ---------------------------------------------------------------------------
// silu + 8 cubic B-spline bases on uniform grid t_m = 0.4*m - 2.2
// ---------------------------------------------------------------------------
__device__ __forceinline__ void kan_feat_u(float x, unsigned short* dst) {
  float s = x / (1.0f + __expf(-x));
  float B[11];
#pragma unroll
  for (int j = 0; j < 11; ++j) {
    float gj = -2.2f + 0.4f * j;
    B[j] = (x >= gj && x < gj + 0.4f) ? 1.0f : 0.0f;
  }
#pragma unroll
  for (int p = 1; p <= 3; ++p) {
    float inv = 1.0f / (0.4f * p);
#pragma unroll
    for (int i = 0; i + p < 11; ++i) {
      float gi = -2.2f + 0.4f * i;
      B[i] = (x - gi) * inv * B[i] + ((gi + 0.4f + 0.4f * p) - x) * inv * B[i + 1];
    }
  }
  dst[0] = bf16b(s);
#pragma unroll
  for (int c = 0; c < 8; ++c) dst[1 + c] = bf16b(B[c]);
}

// ---------------------------------------------------------------------------
// Pack two adjacent input-features per thread -> 9 dword stores.
// dst row = o*rowMul + rowBase (rowMul=2 interleaves two layers).
// ---------------------------------------------------------------------------
__global__ void pack_kan_w(const float* __restrict__ bw, const float* __restrict__ sw,
                           __hip_bfloat16* __restrict__ W, int K, int inShift,
                           int rowMul, int rowBase, size_t totalPairs) {
  size_t t = (size_t)blockIdx.x * blockDim.x + threadIdx.x;
  if (t >= totalPairs) return;
  size_t o = t >> (inShift - 1);
  size_t ip = (t & (((size_t)1 << (inShift - 1)) - 1)) * 2;
  size_t e0 = (o << inShift) + ip;
  float2 b = *(const float2*)(bw + e0);
  const float4* sp = (const float4*)(sw + e0 * 8);
  float4 s0 = sp[0], s1 = sp[1], s2 = sp[2], s3 = sp[3];
  unsigned short h[18];
  h[0] = bf16b(b.x);
  h[1] = bf16b(s0.x); h[2] = bf16b(s0.y); h[3] = bf16b(s0.z); h[4] = bf16b(s0.w);
  h[5] = bf16b(s1.x); h[6] = bf16b(s1.y); h[7] = bf16b(s1.z); h[8] = bf16b(s1.w);
  h[9] = bf16b(b.y);
  h[10] = bf16b(s2.x); h[11] = bf16b(s2.y); h[12] = bf16b(s2.z); h[13] = bf16b(s2.w);
  h[14] = bf16b(s3.x); h[15] = bf16b(s3.y); h[16] = bf16b(s3.z); h[17] = bf16b(s3.w);
  uint32_t* dst = (uint32_t*)(W + (o * rowMul + rowBase) * (size_t)K + ip * NC);
#pragma unroll
  for (int k = 0; k < 9; ++k) dst[k] = (uint32_t)h[2 * k] | ((uint32_t)h[2 * k + 1] << 16);
}

// A1 from x; two elements per thread
__global__ void build_a1(const float* __restrict__ x, __hip_bfloat16* __restrict__ A1) {
  size_t t = (size_t)blockIdx.x * blockDim.x + threadIdx.x;
  if (t >= (size_t)NTOK * D_MODEL / 2) return;
  size_t n = t >> 9;
  size_t ip = (t & 511) * 2;
  float2 xv = *(const float2*)(x + n * D_MODEL + ip);
  unsigned short h[18];
  kan_feat_u(xv.x, h);
  kan_feat_u(xv.y, h + 9);
  uint32_t* dst = (uint32_t*)(A1 + n * (size_t)K1 + ip * NC);
#pragma unroll
  for (int k = 0; k < 9; ++k) dst[k] = (uint32_t)h[2 * k] | ((uint32_t)h[2 * k + 1] << 16);
}

// fallback only: h = Hc[:, :4096] * Hc[:, 4096:]; two j per thread
template <typename HT>
__global__ void glu_a3(const HT* __restrict__ Hc, __hip_bfloat16* __restrict__ A3c) {
  size_t t = (size_t)blockIdx.x * blockDim.x + threadIdx.x;
  if (t >= (size_t)CHUNK * D_FF / 2) return;
  size_t n = t >> 11;
  size_t jp = (t & 2047) * 2;
  float a0, a1, c0, c1;
  if constexpr (std::is_same<HT, float>::value) {
    float2 u = *(const float2*)(Hc + n * 8192 + jp);
    float2 v = *(const float2*)(Hc + n * 8192 + 4096 + jp);
    a0 = u.x; a1 = u.y; c0 = v.x; c1 = v.y;
  } else {
    a0 = __bfloat162float(Hc[n * 8192 + jp]);
    a1 = __bfloat162float(Hc[n * 8192 + jp + 1]);
    c0 = __bfloat162float(Hc[n * 8192 + 4096 + jp]);
    c1 = __bfloat162float(Hc[n * 8192 + 4096 + jp + 1]);
  }
  unsigned short h[18];
  kan_feat_u(a0 * c0, h);
  kan_feat_u(a1 * c1, h + 9);
  uint32_t* dst = (uint32_t*)(A3c + n * (size_t)K3 + jp * NC);
#pragma unroll
  for (int k = 0; k < 9; ++k) dst[k] = (uint32_t)h[2 * k] | ((uint32_t)h[2 * k + 1] << 16);
}

// ---------------------------------------------------------------------------
// 256x256 bf16 GEMM, ring-4 pipelined (R3 body). FUSE: GLU+KAN epilogue.
// ---------------------------------------------------------------------------
#define STAGE(Ts)                                                                        \
  {                                                                                      \
    const int _sl = ((Ts) & 3) * 32768;                                                  \
    const size_t _ko = (size_t)(Ts) * 64;                                                \
    __builtin_amdgcn_global_load_lds(                                                    \
        (const __attribute__((address_space(1))) void*)(gA0 + _ko),                      \
        (__attribute__((address_space(3))) void*)(lds_raw + _sl + dA0), 16, 0, 0);       \
    __builtin_amdgcn_global_load_lds(                                                    \
        (const __attribute__((address_space(1))) void*)(gA1 + _ko),                      \
        (__attribute__((address_space(3))) void*)(lds_raw + _sl + dA1), 16, 0, 0);       \
    __builtin_amdgcn_global_load_lds(                                                    \
        (const __attribute__((address_space(1))) void*)(gB0 + _ko),                      \
        (__attribute__((address_space(3))) void*)(lds_raw + _sl + dB0), 16, 0, 0);       \
    __builtin_amdgcn_global_load_lds(                                                    \
        (const __attribute__((address_space(1))) void*)(gB1 + _ko),                      \
        (__attribute__((address_space(3))) void*)(lds_raw + _sl + dB1), 16, 0, 0);       \
  }

template <typename CT, bool FUSE>
__global__ __launch_bounds__(512, 2) void gemm256(
    const __hip_bfloat16* __restrict__ A, const __hip_bfloat16* __restrict__ Bw,
    CT* __restrict__ Cp, int N, int K, int kLen,
    __hip_bfloat16* __restrict__ A3out) {
  __shared__ __align__(16) char lds_raw[4 * 32768];  // 128 KB

  const int tid = threadIdx.x;
  const int wid = tid >> 6, lane = tid & 63;
  const int wr = wid >> 2, wc = wid & 3;

  // bijective XCD swizzle (T1); all grids have nwg % 8 == 0
  const int nwg = gridDim.x * gridDim.y;
  const int orig = blockIdx.y * gridDim.x + blockIdx.x;
  const int q = nwg >> 3, r = nwg & 7;
  const int xcd = orig & 7, lid = orig >> 3;
  const int wg = (xcd < r ? xcd * (q + 1) : r * (q + 1) + (xcd - r) * q) + lid;
  const int bx = wg % gridDim.x, by = wg / gridDim.x;

  const size_t brow = (size_t)by * 256;
  const size_t bcol = (size_t)bx * 256;
  const int kStart = (int)blockIdx.z * kLen;
  const int NT = kLen / 32;

  // staging: wave wid covers 16 rows of each half; 16B grp pre-swizzled
  const int kbx = (lane & 3) ^ ((lane >> 3) & 3);
  const int rsub = lane >> 2;
  const char* gA0 = (const char*)A +
      ((brow + (size_t)(wid * 16 + rsub)) * (size_t)K + kStart + kbx * 8) * 2;
  const char* gA1 = (const char*)A +
      ((brow + 128 + (size_t)(wid * 16 + rsub)) * (size_t)K + kStart + kbx * 8) * 2;
  const char* gB0 = (const char*)Bw +
      ((bcol + (size_t)(wid * 16 + rsub)) * (size_t)K + kStart + kbx * 8) * 2;
  const char* gB1 = (const char*)Bw +
      ((bcol + 128 + (size_t)(wid * 16 + rsub)) * (size_t)K + kStart + kbx * 8) * 2;
  const int dA0 = wid * 1024;
  const int dA1 = 8192 + wid * 1024;
  const int dB0 = 16384 + wid * 1024;
  const int dB1 = 24576 + wid * 1024;

  // ds_read fragment offsets (swizzled)
  const int fkb = (lane >> 4) ^ ((lane >> 1) & 3);
  const int aoff = (wr * 128 + (lane & 15)) * 64 + fkb * 16;
  const int boff = 16384 + (wc * 64 + (lane & 15)) * 64 + fkb * 16;

  f32x4 acc[8][4] = {};

  // prologue: stage tiles 0,1,2; ensure tile 0 landed (tiles 1,2 in flight)
  STAGE(0);
  STAGE(1);
  STAGE(2);
  asm volatile("s_waitcnt vmcnt(8)" ::: "memory");
  __builtin_amdgcn_s_barrier();

  for (int T = 0; T < NT; ++T) {
    if (T + 3 < NT) STAGE(T + 3);

    const int sl = (T & 3) * 32768;
    bf16x8 af[8], bfr[4];
#pragma unroll
    for (int mf = 0; mf < 8; ++mf)
      af[mf] = *(const bf16x8*)(lds_raw + sl + aoff + mf * 1024);
#pragma unroll
    for (int nf = 0; nf < 4; ++nf)
      bfr[nf] = *(const bf16x8*)(lds_raw + sl + boff + nf * 1024);

    __builtin_amdgcn_s_setprio(1);
#pragma unroll
    for (int mf = 0; mf < 8; ++mf)
#pragma unroll
      for (int nf = 0; nf < 4; ++nf)
        acc[mf][nf] =
            __builtin_amdgcn_mfma_f32_16x16x32_bf16(af[mf], bfr[nf], acc[mf][nf], 0, 0, 0);
    __builtin_amdgcn_s_setprio(0);

    if (T + 4 <= NT) {
      asm volatile("s_waitcnt vmcnt(8)" ::: "memory");
    } else if (T + 3 == NT) {
      asm volatile("s_waitcnt vmcnt(4)" ::: "memory");
    } else if (T + 2 == NT) {
      asm volatile("s_waitcnt vmcnt(0)" ::: "memory");
    }
    asm volatile("s_waitcnt lgkmcnt(0)" ::: "memory");
    __builtin_amdgcn_s_barrier();
  }

  if constexpr (FUSE) {
    // ---- GLU + KAN-feature epilogue: A3[n][pg*9+f] = feat(h1*h2) ----
    // col = wc*64 + nf*16 + (lane&15); pair partner = lane^1.
    float* gbuf = (float*)lds_raw;  // 16 slices x 16 rows x 128 pairs f32
#pragma unroll
    for (int mf = 0; mf < 8; ++mf) {
      const int s = wr * 8 + mf;
#pragma unroll
      for (int nf = 0; nf < 4; ++nf) {
#pragma unroll
        for (int rr = 0; rr < 4; ++rr) {
          float v = acc[mf][nf][rr];
          float w = __shfl_xor(v, 1, 64);
          if (!(lane & 1)) {
            const int r4 = (lane >> 4) * 4 + rr;
            const int ploc = wc * 32 + nf * 8 + ((lane & 14) >> 1);
            gbuf[s * 2048 + r4 * 128 + ploc] = v * w;
          }
        }
      }
    }
    __builtin_amdgcn_s_barrier();
    const int p2 = tid & 63;   // pair-pair index (handles pairs 2p2, 2p2+1)
    const int rb = tid >> 6;   // base row
    for (int k = 0; k < 32; ++k) {
      const int rr_ = rb + 8 * k;  // 0..255
      const int s = rr_ >> 4, rl = rr_ & 15;
      float g0 = gbuf[s * 2048 + rl * 128 + 2 * p2];
      float g1 = gbuf[s * 2048 + rl * 128 + 2 * p2 + 1];
      unsigned short h[18];
      kan_feat_u(g0, h);
      kan_feat_u(g1, h + 9);
      const size_t n = brow + rr_;
      const size_t pg = (bcol >> 1) + 2 * p2;
      uint32_t* dst = (uint32_t*)(A3out + n * (size_t)K3 + pg * NC);
#pragma unroll
      for (int qq = 0; qq < 9; ++qq)
        dst[qq] = (uint32_t)h[2 * qq] | ((uint32_t)h[2 * qq + 1] << 16);
    }
  } else {
    // plain epilogue: C/D layout col=lane&15, row=(lane>>4)*4+r
#pragma unroll
    for (int mf = 0; mf < 8; ++mf)
#pragma unroll
      for (int nf = 0; nf < 4; ++nf) {
        const size_t r0 = brow + wr * 128 + mf * 16 + (lane >> 4) * 4;
        const size_t c0 = bcol + wc * 64 + nf * 16 + (lane & 15);
        const size_t M = (size_t)gridDim.y * 256;
        CT* C = Cp + (size_t)blockIdx.z * M * (size_t)N;
#pragma unroll
        for (int rr = 0; rr < 4; ++rr) {
          float v = acc[mf][nf][rr];
          if constexpr (std::is_same<CT, float>::value)
            C[(r0 + rr) * (size_t)N + c0] = v;
          else
            C[(r0 + rr) * (size_t)N + c0] = __float2bfloat16(v);
        }
      }
  }
}

// sum nslice split-K partials (float4-vectorized)
__global__ void reduceK(const float* __restrict__ P, float* __restrict__ out,
                        size_t quarter, int nslice) {
  size_t t = (size_t)blockIdx.x * blockDim.x + threadIdx.x;
  if (t >= quarter) return;
  const float4* p = (const float4*)P;
  float4 a = p[t];
  for (int s = 1; s < nslice; ++s) {
    float4 b = p[(size_t)s * quarter + t];
    a.x += b.x; a.y += b.y; a.z += b.z; a.w += b.w;
  }
  ((float4*)out)[t] = a;
}

// ---------------------------------------------------------------------------
extern "C" void kernel_launch(void* const* d_in, const int* in_sizes, int n_in,
                              void* d_out, int out_size, void* d_ws, size_t ws_size,
                              hipStream_t stream) {
  const float* x   = (const float*)d_in[0];
  const float* bw1 = (const float*)d_in[1];
  const float* sw1 = (const float*)d_in[2];
  const float* bw2 = (const float*)d_in[3];
  const float* sw2 = (const float*)d_in[4];
  const float* bw3 = (const float*)d_in[5];
  const float* sw3 = (const float*)d_in[6];
  float* out = (float*)d_out;
  char* ws = (char*)d_ws;

  const size_t W12_B  = (size_t)8192 * K1 * 2;   // 150,994,944
  const size_t A1_B   = (size_t)NTOK * K1 * 2;   //  75,497,472
  const size_t A3F_B  = (size_t)NTOK * K3 * 2;   // 301,989,888
  const size_t A3C_B  = (size_t)CHUNK * K3 * 2;  //  75,497,472
  const size_t HF32_B = (size_t)NTOK * 8192 * 4; // 134,217,728

  const bool fused = ws_size >= W12_B + A1_B + A3F_B;  // 528,482,304
  const bool hF32  = ws_size >= W12_B + A1_B + HF32_B; // 360,710,144 (fallback)

  __hip_bfloat16* W12 = (__hip_bfloat16*)(ws);
  __hip_bfloat16* A1  = (__hip_bfloat16*)(ws + W12_B);
  __hip_bfloat16* W3  = A1;  // A1 dead after GEMM1

  size_t pairs12 = (size_t)D_FF * D_MODEL / 2;
  int blocks12 = (int)((pairs12 + 255) / 256);
  size_t pairs3 = (size_t)D_MODEL * D_FF / 2;
  int blocks3 = (int)((pairs3 + 255) / 256);
  size_t pairsA1 = (size_t)NTOK * D_MODEL / 2;

  if (fused) {
    // layout: [W12 | A1->W3 | A3 full]; Par reuses W12 region after GEMM1
    __hip_bfloat16* A3f = (__hip_bfloat16*)(ws + W12_B + A1_B);
    float*          Par = (float*)(ws);  // 4 x 4096 x 1024 f32 = 67MB

    pack_kan_w<<<blocks12, 256, 0, stream>>>(bw1, sw1, W12, K1, 10, 2, 0, pairs12);
    pack_kan_w<<<blocks12, 256, 0, stream>>>(bw2, sw2, W12, K1, 10, 2, 1, pairs12);
    build_a1<<<(int)((pairsA1 + 255) / 256), 256, 0, stream>>>(x, A1);
    // GEMM1 + fused GLU/KAN epilogue -> A3
    gemm256<float, true><<<dim3(8192 / 256, NTOK / 256, 1), 512, 0, stream>>>(
        A1, W12, nullptr, 8192, K1, K1, A3f);
    pack_kan_w<<<blocks3, 256, 0, stream>>>(bw3, sw3, W3, K3, 12, 1, 0, pairs3);
    // GEMM2 full, split-K=4
    gemm256<float, false><<<dim3(D_MODEL / 256, NTOK / 256, SPLITKF), 512, 0, stream>>>(
        A3f, W3, Par, D_MODEL, K3, K3 / SPLITKF, nullptr);
    size_t quarter = (size_t)NTOK * D_MODEL / 4;
    reduceK<<<(int)((quarter + 255) / 256), 256, 0, stream>>>(Par, out, quarter, SPLITKF);
  } else {
    // fallback: R7 flow (H + glu_a3 + chunked GEMM2)
    void*           Hv  = (void*)(ws + W12_B + A1_B);
    __hip_bfloat16* A3c = (__hip_bfloat16*)(ws);        // W12 dead after GEMM1
    float*          Par = (float*)(ws + A3C_B);

    pack_kan_w<<<blocks12, 256, 0, stream>>>(bw1, sw1, W12, K1, 10, 1, 0, pairs12);
    pack_kan_w<<<blocks12, 256, 0, stream>>>(bw2, sw2, W12, K1, 10, 1, 4096, pairs12);
    build_a1<<<(int)((pairsA1 + 255) / 256), 256, 0, stream>>>(x, A1);
    if (hF32)
      gemm256<float, false><<<dim3(8192 / 256, NTOK / 256, 1), 512, 0, stream>>>(
          A1, W12, (float*)Hv, 8192, K1, K1, nullptr);
    else
      gemm256<__hip_bfloat16, false><<<dim3(8192 / 256, NTOK / 256, 1), 512, 0, stream>>>(
          A1, W12, (__hip_bfloat16*)Hv, 8192, K1, K1, nullptr);
    pack_kan_w<<<blocks3, 256, 0, stream>>>(bw3, sw3, W3, K3, 12, 1, 0, pairs3);
    for (int c = 0; c < NTOK / CHUNK; ++c) {
      size_t pairsG = (size_t)CHUNK * D_FF / 2;
      int blocksG = (int)((pairsG + 255) / 256);
      if (hF32)
        glu_a3<float><<<blocksG, 256, 0, stream>>>(
            (const float*)Hv + (size_t)c * CHUNK * 8192, A3c);
      else
        glu_a3<__hip_bfloat16><<<blocksG, 256, 0, stream>>>(
            (const __hip_bfloat16*)Hv + (size_t)c * CHUNK * 8192, A3c);
      gemm256<float, false><<<dim3(D_MODEL / 256, CHUNK / 256, SPLITK2), 512, 0, stream>>>(
          A3c, W3, Par, D_MODEL, K3, K3 / SPLITK2, nullptr);
      size_t quarter = (size_t)CHUNK * D_MODEL / 4;
      reduceK<<<(int)((quarter + 255) / 256), 256, 0, stream>>>(
          Par, out + (size_t)c * CHUNK * D_MODEL, quarter, SPLITK2);
    }
  }
}